// Round 1
// baseline (7510.722 us; speedup 1.0000x reference)
//
#include <hip/hip_runtime.h>
#include <hip/hip_bf16.h>

#define B_  16
#define S_  512
#define D_  768
#define H_  12
#define DH_ 64
#define L_  12
#define FF_ 3072
#define EPS_ 1e-5f

typedef __hip_bfloat16 bf16;
typedef __attribute__((ext_vector_type(8))) short short8;   // 8 bf16 = 4 VGPRs (MFMA A/B frag)
typedef __attribute__((ext_vector_type(4))) float floatx4;  // MFMA C/D frag

// ---------------------------------------------------------------------------
// Weight transpose+convert: in (batch, R, C) fp32 -> out (batch, C, R) bf16
// ---------------------------------------------------------------------------
__global__ void wtrans_kernel(const float* __restrict__ in, bf16* __restrict__ out,
                              int R, int C)
{
    __shared__ float tile[32][33];
    long z = blockIdx.z;
    const float* ip = in + z * (long)R * C;
    bf16* op = out + z * (long)R * C;
    int r0 = blockIdx.y * 32, c0 = blockIdx.x * 32;
    for (int i = threadIdx.y; i < 32; i += 8)
        tile[i][threadIdx.x] = ip[(long)(r0 + i) * C + c0 + threadIdx.x];
    __syncthreads();
    for (int i = threadIdx.y; i < 32; i += 8)
        op[(long)(c0 + i) * R + r0 + threadIdx.x] = __float2bfloat16(tile[threadIdx.x][i]);
}

// ---------------------------------------------------------------------------
// V transpose: v (b, s, h, dh) bf16 -> vt (b, h, dh, s) bf16
// ---------------------------------------------------------------------------
__global__ void transpose_v_kernel(const bf16* __restrict__ v, bf16* __restrict__ vt)
{
    __shared__ bf16 tile[32][33];
    int bh = blockIdx.z;
    int b = bh / H_, h = bh - b * H_;
    int s0 = blockIdx.x * 32, d0 = blockIdx.y * 32;
    for (int i = threadIdx.y; i < 32; i += 8)
        tile[i][threadIdx.x] = v[((long)(b * S_ + s0 + i)) * D_ + h * DH_ + d0 + threadIdx.x];
    __syncthreads();
    for (int i = threadIdx.y; i < 32; i += 8)
        vt[((long)bh * DH_ + d0 + i) * S_ + s0 + threadIdx.x] = tile[threadIdx.x][i];
}

// ---------------------------------------------------------------------------
// Embedding + LayerNorm -> x fp32.  One block per token, 256 thr x 3 elems.
// ---------------------------------------------------------------------------
__global__ __launch_bounds__(256) void embed_ln_kernel(
    const int* __restrict__ idx, const float* __restrict__ tok,
    const float* __restrict__ seg, const float* __restrict__ pos,
    const float* __restrict__ g, const float* __restrict__ b,
    float* __restrict__ x)
{
    __shared__ float red[8];
    int t = blockIdx.x;
    int si = t & (S_ - 1);
    int token = idx[t];
    int sg = (si >= S_ / 2 + 1) ? 1 : 0;
    float e[3]; float s1 = 0.f, s2 = 0.f;
#pragma unroll
    for (int i = 0; i < 3; i++) {
        int c = threadIdx.x + i * 256;
        float v = tok[(long)token * D_ + c] + seg[sg * D_ + c] + pos[(long)si * D_ + c];
        e[i] = v; s1 += v; s2 += v * v;
    }
    for (int o = 32; o > 0; o >>= 1) { s1 += __shfl_down(s1, o); s2 += __shfl_down(s2, o); }
    if ((threadIdx.x & 63) == 0) { red[(threadIdx.x >> 6) * 2] = s1; red[(threadIdx.x >> 6) * 2 + 1] = s2; }
    __syncthreads();
    s1 = red[0] + red[2] + red[4] + red[6];
    s2 = red[1] + red[3] + red[5] + red[7];
    float mu = s1 * (1.f / D_);
    float var = s2 * (1.f / D_) - mu * mu;
    float rs = rsqrtf(var + EPS_);
#pragma unroll
    for (int i = 0; i < 3; i++) {
        int c = threadIdx.x + i * 256;
        x[(long)t * D_ + c] = (e[i] - mu) * rs * g[c] + b[c];
    }
}

// ---------------------------------------------------------------------------
// LayerNorm: x fp32 -> out (bf16 or fp32).  One block per token.
// ---------------------------------------------------------------------------
__device__ inline void storev(bf16* p, float v)  { *p = __float2bfloat16(v); }
__device__ inline void storev(float* p, float v) { *p = v; }

template<typename OUT>
__global__ __launch_bounds__(256) void ln_kernel(
    const float* __restrict__ x, const float* __restrict__ g, const float* __restrict__ b,
    OUT* __restrict__ out)
{
    __shared__ float red[8];
    long t = blockIdx.x;
    float e[3]; float s1 = 0.f, s2 = 0.f;
#pragma unroll
    for (int i = 0; i < 3; i++) {
        int c = threadIdx.x + i * 256;
        float v = x[t * D_ + c];
        e[i] = v; s1 += v; s2 += v * v;
    }
    for (int o = 32; o > 0; o >>= 1) { s1 += __shfl_down(s1, o); s2 += __shfl_down(s2, o); }
    if ((threadIdx.x & 63) == 0) { red[(threadIdx.x >> 6) * 2] = s1; red[(threadIdx.x >> 6) * 2 + 1] = s2; }
    __syncthreads();
    s1 = red[0] + red[2] + red[4] + red[6];
    s2 = red[1] + red[3] + red[5] + red[7];
    float mu = s1 * (1.f / D_);
    float var = s2 * (1.f / D_) - mu * mu;
    float rs = rsqrtf(var + EPS_);
#pragma unroll
    for (int i = 0; i < 3; i++) {
        int c = threadIdx.x + i * 256;
        storev(out + t * D_ + c, (e[i] - mu) * rs * g[c] + b[c]);
    }
}

// ---------------------------------------------------------------------------
// Row softmax over 512 cols (in-place, bf16), scale applied to logits.
// ---------------------------------------------------------------------------
__global__ __launch_bounds__(256) void softmax_kernel(bf16* __restrict__ s, float scale)
{
    __shared__ float red[4];
    long row = blockIdx.x;
    bf16* p = s + row * S_;
    float v0 = scale * __bfloat162float(p[threadIdx.x]);
    float v1 = scale * __bfloat162float(p[threadIdx.x + 256]);
    float m = fmaxf(v0, v1);
    for (int o = 32; o > 0; o >>= 1) m = fmaxf(m, __shfl_down(m, o));
    if ((threadIdx.x & 63) == 0) red[threadIdx.x >> 6] = m;
    __syncthreads();
    m = fmaxf(fmaxf(red[0], red[1]), fmaxf(red[2], red[3]));
    __syncthreads();
    v0 = __expf(v0 - m); v1 = __expf(v1 - m);
    float sum = v0 + v1;
    for (int o = 32; o > 0; o >>= 1) sum += __shfl_down(sum, o);
    if ((threadIdx.x & 63) == 0) red[threadIdx.x >> 6] = sum;
    __syncthreads();
    sum = red[0] + red[1] + red[2] + red[3];
    float inv = 1.f / sum;
    p[threadIdx.x]       = __float2bfloat16(v0 * inv);
    p[threadIdx.x + 256] = __float2bfloat16(v1 * inv);
}

// ---------------------------------------------------------------------------
// MFMA GEMM: C[M,N] = A[M,K] * Bt[N,K]^T.  128x128 tile, BK=32, 4 waves.
// EPI 0: C -> bf16.  EPI 1: relu(C + bias) -> bf16.  EPI 2: Cf += C + bias (fp32).
// Batched via blockIdx.z decomposed as (i1, i2) with i2 = z % batchH.
// ---------------------------------------------------------------------------
#define LSTR 72   // LDS row stride (bf16 elems): 144 B keeps b128 reads 16B-aligned, ~2-way banks

template<int EPI>
__global__ __launch_bounds__(256) void gemm_bt(
    const bf16* __restrict__ A, const bf16* __restrict__ Bt,
    bf16* __restrict__ Cb, float* __restrict__ Cf, const float* __restrict__ bias,
    int M, int N, int K, int lda, int ldb, int ldc,
    int batchH, long sA1, long sA2, long sB1, long sB2, long sC1, long sC2)
{
    __shared__ __align__(16) bf16 As[128 * LSTR];
    __shared__ __align__(16) bf16 Bs[128 * LSTR];

    const int z = blockIdx.z;
    const int i1 = z / batchH, i2 = z - i1 * batchH;
    A  += i1 * sA1 + i2 * sA2;
    Bt += i1 * sB1 + i2 * sB2;
    const long coff = i1 * sC1 + i2 * sC2;

    const int tid  = threadIdx.x;
    const int lane = tid & 63, wave = tid >> 6;
    const int wm = wave >> 1, wn = wave & 1;
    const int lh = lane & 15, quad = lane >> 4;
    const int tileM = blockIdx.y * 128, tileN = blockIdx.x * 128;

    floatx4 acc[4][4];
#pragma unroll
    for (int i = 0; i < 4; i++)
#pragma unroll
        for (int j = 0; j < 4; j++)
#pragma unroll
            for (int r = 0; r < 4; r++) acc[i][j][r] = 0.f;

    for (int kt = 0; kt < K; kt += 32) {
#pragma unroll
        for (int c = 0; c < 2; c++) {
            int id = tid + c * 256;
            int r = id >> 2, sg = id & 3;
            uint4 va = make_uint4(0, 0, 0, 0);
            int gm = tileM + r;
            if (gm < M) va = *(const uint4*)(A + (long)gm * lda + kt + sg * 8);
            *(uint4*)(As + r * LSTR + sg * 8) = va;
            uint4 vb = make_uint4(0, 0, 0, 0);
            int gn = tileN + r;
            if (gn < N) vb = *(const uint4*)(Bt + (long)gn * ldb + kt + sg * 8);
            *(uint4*)(Bs + r * LSTR + sg * 8) = vb;
        }
        __syncthreads();
        short8 af[4], bfr[4];
#pragma unroll
        for (int i = 0; i < 4; i++)
            af[i] = *(const short8*)(As + (wm * 64 + i * 16 + lh) * LSTR + quad * 8);
#pragma unroll
        for (int j = 0; j < 4; j++)
            bfr[j] = *(const short8*)(Bs + (wn * 64 + j * 16 + lh) * LSTR + quad * 8);
#pragma unroll
        for (int i = 0; i < 4; i++)
#pragma unroll
            for (int j = 0; j < 4; j++)
                acc[i][j] = __builtin_amdgcn_mfma_f32_16x16x32_bf16(af[i], bfr[j], acc[i][j], 0, 0, 0);
        __syncthreads();
    }

#pragma unroll
    for (int i = 0; i < 4; i++) {
#pragma unroll
        for (int j = 0; j < 4; j++) {
            int col = tileN + wn * 64 + j * 16 + lh;
            if (col >= N) continue;
#pragma unroll
            for (int r = 0; r < 4; r++) {
                int row = tileM + wm * 64 + i * 16 + quad * 4 + r;
                if (row >= M) continue;
                float v = acc[i][j][r];
                long o = coff + (long)row * ldc + col;
                if (EPI == 0) {
                    Cb[o] = __float2bfloat16(v);
                } else if (EPI == 1) {
                    v += bias[col];
                    Cb[o] = __float2bfloat16(v > 0.f ? v : 0.f);
                } else {
                    Cf[o] += v + bias[col];
                }
            }
        }
    }
}

// ---------------------------------------------------------------------------
extern "C" void kernel_launch(void* const* d_in, const int* in_sizes, int n_in,
                              void* d_out, int out_size, void* d_ws, size_t ws_size,
                              hipStream_t stream)
{
    const int*   idx  = (const int*)d_in[0];
    const float* tok  = (const float*)d_in[1];
    const float* segE = (const float*)d_in[2];
    const float* pos  = (const float*)d_in[3];
    const float* lng  = (const float*)d_in[4];
    const float* lnb  = (const float*)d_in[5];
    const float* Wq   = (const float*)d_in[6];
    const float* Wk   = (const float*)d_in[7];
    const float* Wv   = (const float*)d_in[8];
    const float* Wo   = (const float*)d_in[9];
    const float* bo   = (const float*)d_in[10];
    const float* ln1g = (const float*)d_in[11];
    const float* ln1b = (const float*)d_in[12];
    const float* ln2g = (const float*)d_in[13];
    const float* ln2b = (const float*)d_in[14];
    const float* W1   = (const float*)d_in[15];
    const float* b1   = (const float*)d_in[16];
    const float* W2   = (const float*)d_in[17];
    const float* b2   = (const float*)d_in[18];
    const float* lnfg = (const float*)d_in[19];
    const float* lnfb = (const float*)d_in[20];

    char* w = (char*)d_ws;
    size_t off = 0;
    auto alloc = [&](size_t bytes) { void* p = w + off; off += (bytes + 255) & ~255UL; return p; };

    const long LDD = (long)D_ * D_;            // 589824 per-layer weight elems
    bf16* WqT = (bf16*)alloc((size_t)L_ * LDD * 2);
    bf16* WkT = (bf16*)alloc((size_t)L_ * LDD * 2);
    bf16* WvT = (bf16*)alloc((size_t)L_ * LDD * 2);
    bf16* WoT = (bf16*)alloc((size_t)L_ * LDD * 2);
    bf16* W1T = (bf16*)alloc((size_t)L_ * D_ * FF_ * 2);
    bf16* W2T = (bf16*)alloc((size_t)L_ * D_ * FF_ * 2);
    float* x  = (float*)alloc((size_t)B_ * S_ * D_ * 4);
    bf16* h   = (bf16*)alloc((size_t)B_ * S_ * D_ * 2);
    bf16* qb  = (bf16*)alloc((size_t)B_ * S_ * D_ * 2);   // also reused as o (attn out)
    bf16* kb  = (bf16*)alloc((size_t)B_ * S_ * D_ * 2);
    bf16* vb  = (bf16*)alloc((size_t)B_ * S_ * D_ * 2);
    bf16* vt  = (bf16*)alloc((size_t)B_ * S_ * D_ * 2);
    bf16* sb  = (bf16*)alloc((size_t)B_ * H_ * S_ * S_ * 2);  // scores/probs; reused as ff
    bf16* ff  = sb;   // FF1 output (50 MB) aliases scores (100 MB) — disjoint in time
    (void)ws_size; (void)n_in; (void)in_sizes;

    dim3 blk256(256), blkT(32, 8);

    // ---- weight prep (bf16, transposed to (N,K) row-major) ----
    wtrans_kernel<<<dim3(DH_ / 32, D_ / 32, L_ * H_), blkT, 0, stream>>>(Wq, WqT, D_, DH_);
    wtrans_kernel<<<dim3(DH_ / 32, D_ / 32, L_ * H_), blkT, 0, stream>>>(Wk, WkT, D_, DH_);
    wtrans_kernel<<<dim3(DH_ / 32, D_ / 32, L_ * H_), blkT, 0, stream>>>(Wv, WvT, D_, DH_);
    wtrans_kernel<<<dim3(D_ / 32, D_ / 32, L_), blkT, 0, stream>>>(Wo, WoT, D_, D_);
    wtrans_kernel<<<dim3(FF_ / 32, D_ / 32, L_), blkT, 0, stream>>>(W1, W1T, D_, FF_);
    wtrans_kernel<<<dim3(D_ / 32, FF_ / 32, L_), blkT, 0, stream>>>(W2, W2T, FF_, D_);

    // ---- embedding + LN ----
    embed_ln_kernel<<<dim3(B_ * S_), blk256, 0, stream>>>(idx, tok, segE, pos, lng, lnb, x);

    const int M = B_ * S_;                  // 8192
    const long sBH = (long)S_ * D_;         // per-b stride in q/k/v
    const long sSS = (long)S_ * S_;

    for (int l = 0; l < L_; l++) {
        // h = LN1(x)
        ln_kernel<bf16><<<dim3(M), blk256, 0, stream>>>(x, ln1g + l * D_, ln1b + l * D_, h);
        // Q, K, V projections (no bias)
        gemm_bt<0><<<dim3(6, 64, 1), blk256, 0, stream>>>(h, WqT + l * LDD, qb, nullptr, nullptr,
            M, D_, D_, D_, D_, D_, 1, 0, 0, 0, 0, 0, 0);
        gemm_bt<0><<<dim3(6, 64, 1), blk256, 0, stream>>>(h, WkT + l * LDD, kb, nullptr, nullptr,
            M, D_, D_, D_, D_, D_, 1, 0, 0, 0, 0, 0, 0);
        gemm_bt<0><<<dim3(6, 64, 1), blk256, 0, stream>>>(h, WvT + l * LDD, vb, nullptr, nullptr,
            M, D_, D_, D_, D_, D_, 1, 0, 0, 0, 0, 0, 0);
        // vt (b,h,dh,s)
        transpose_v_kernel<<<dim3(S_ / 32, DH_ / 32, B_ * H_), blkT, 0, stream>>>(vb, vt);
        // scores = Q K^T  (batched over b*h)
        gemm_bt<0><<<dim3(4, 4, B_ * H_), blk256, 0, stream>>>(qb, kb, sb, nullptr, nullptr,
            S_, S_, DH_, D_, D_, S_, H_,
            sBH, DH_, sBH, DH_, (long)H_ * sSS, sSS);
        // softmax rows (scale 1/sqrt(64))
        softmax_kernel<<<dim3(B_ * H_ * S_), blk256, 0, stream>>>(sb, 0.125f);
        // o = P V   (batched; C written into qb at (b,s,h,dh))
        gemm_bt<0><<<dim3(1, 4, B_ * H_), blk256, 0, stream>>>(sb, vt, qb, nullptr, nullptr,
            S_, DH_, S_, S_, S_, D_, H_,
            (long)H_ * sSS, sSS, (long)H_ * DH_ * S_, (long)DH_ * S_, sBH, (long)DH_);
        // x += o @ Wo + bo
        gemm_bt<2><<<dim3(6, 64, 1), blk256, 0, stream>>>(qb, WoT + l * LDD, nullptr, x, bo + l * D_,
            M, D_, D_, D_, D_, D_, 1, 0, 0, 0, 0, 0, 0);
        // h = LN2(x)
        ln_kernel<bf16><<<dim3(M), blk256, 0, stream>>>(x, ln2g + l * D_, ln2b + l * D_, h);
        // ff = relu(h @ W1 + b1)
        gemm_bt<1><<<dim3(24, 64, 1), blk256, 0, stream>>>(h, W1T + (long)l * D_ * FF_, ff, nullptr, b1 + l * FF_,
            M, FF_, D_, D_, D_, FF_, 1, 0, 0, 0, 0, 0, 0);
        // x += ff @ W2 + b2
        gemm_bt<2><<<dim3(6, 64, 1), blk256, 0, stream>>>(ff, W2T + (long)l * D_ * FF_, nullptr, x, b2 + l * D_,
            M, D_, FF_, FF_, FF_, D_, 1, 0, 0, 0, 0, 0, 0);
    }

    // final LN -> d_out (fp32)
    ln_kernel<float><<<dim3(M), blk256, 0, stream>>>(x, lnfg, lnfb, (float*)d_out);
}

// Round 2
// 5675.644 us; speedup vs baseline: 1.3233x; 1.3233x over previous
//
#include <hip/hip_runtime.h>
#include <hip/hip_bf16.h>

#define B_  16
#define S_  512
#define D_  768
#define H_  12
#define DH_ 64
#define L_  12
#define FF_ 3072
#define EPS_ 1e-5f

typedef __hip_bfloat16 bf16;
typedef __attribute__((ext_vector_type(8))) short short8;   // 8 bf16 = 4 VGPRs (MFMA A/B frag)
typedef __attribute__((ext_vector_type(4))) float floatx4;  // MFMA C/D frag

// direct global->LDS, 16B per lane; LDS dest = wave-uniform base + lane*16
#define GLOAD_LDS16(g, l) __builtin_amdgcn_global_load_lds( \
    (const __attribute__((address_space(1))) unsigned int*)(g), \
    (__attribute__((address_space(3))) unsigned int*)(l), 16, 0, 0)

// ---------------------------------------------------------------------------
// Weight transpose+convert: in (z, R, C) fp32 -> out (i1*os1 + i2*os2) (C, R) bf16
// z = i1*batchH + i2
// ---------------------------------------------------------------------------
__global__ void wtrans_kernel(const float* __restrict__ in, bf16* __restrict__ out,
                              int R, int C, int batchH, long os1, long os2)
{
    __shared__ float tile[32][33];
    int z = blockIdx.z;
    int i1 = z / batchH, i2 = z - i1 * batchH;
    const float* ip = in + (long)z * R * C;
    bf16* op = out + i1 * os1 + i2 * os2;
    int r0 = blockIdx.y * 32, c0 = blockIdx.x * 32;
    for (int i = threadIdx.y; i < 32; i += 8)
        tile[i][threadIdx.x] = ip[(long)(r0 + i) * C + c0 + threadIdx.x];
    __syncthreads();
    for (int i = threadIdx.y; i < 32; i += 8)
        op[(long)(c0 + i) * R + r0 + threadIdx.x] = __float2bfloat16(tile[threadIdx.x][i]);
}

// ---------------------------------------------------------------------------
// V transpose: v (b, s, h, dh) bf16 -> vt (b, h, dh, s) bf16
// ---------------------------------------------------------------------------
__global__ void transpose_v_kernel(const bf16* __restrict__ v, bf16* __restrict__ vt)
{
    __shared__ bf16 tile[32][33];
    int bh = blockIdx.z;
    int b = bh / H_, h = bh - b * H_;
    int s0 = blockIdx.x * 32, d0 = blockIdx.y * 32;
    for (int i = threadIdx.y; i < 32; i += 8)
        tile[i][threadIdx.x] = v[((long)(b * S_ + s0 + i)) * D_ + h * DH_ + d0 + threadIdx.x];
    __syncthreads();
    for (int i = threadIdx.y; i < 32; i += 8)
        vt[((long)bh * DH_ + d0 + i) * S_ + s0 + threadIdx.x] = tile[threadIdx.x][i];
}

// ---------------------------------------------------------------------------
// Embedding + LayerNorm -> x fp32.  One block per token, 256 thr x 3 elems.
// ---------------------------------------------------------------------------
__global__ __launch_bounds__(256) void embed_ln_kernel(
    const int* __restrict__ idx, const float* __restrict__ tok,
    const float* __restrict__ seg, const float* __restrict__ pos,
    const float* __restrict__ g, const float* __restrict__ b,
    float* __restrict__ x)
{
    __shared__ float red[8];
    int t = blockIdx.x;
    int si = t & (S_ - 1);
    int token = idx[t];
    int sg = (si >= S_ / 2 + 1) ? 1 : 0;
    float e[3]; float s1 = 0.f, s2 = 0.f;
#pragma unroll
    for (int i = 0; i < 3; i++) {
        int c = threadIdx.x + i * 256;
        float v = tok[(long)token * D_ + c] + seg[sg * D_ + c] + pos[(long)si * D_ + c];
        e[i] = v; s1 += v; s2 += v * v;
    }
    for (int o = 32; o > 0; o >>= 1) { s1 += __shfl_down(s1, o); s2 += __shfl_down(s2, o); }
    if ((threadIdx.x & 63) == 0) { red[(threadIdx.x >> 6) * 2] = s1; red[(threadIdx.x >> 6) * 2 + 1] = s2; }
    __syncthreads();
    s1 = red[0] + red[2] + red[4] + red[6];
    s2 = red[1] + red[3] + red[5] + red[7];
    float mu = s1 * (1.f / D_);
    float var = s2 * (1.f / D_) - mu * mu;
    float rs = rsqrtf(var + EPS_);
#pragma unroll
    for (int i = 0; i < 3; i++) {
        int c = threadIdx.x + i * 256;
        x[(long)t * D_ + c] = (e[i] - mu) * rs * g[c] + b[c];
    }
}

// ---------------------------------------------------------------------------
// LayerNorm: x fp32 -> out (bf16 or fp32).  One block per token.
// ---------------------------------------------------------------------------
__device__ inline void storev(bf16* p, float v)  { *p = __float2bfloat16(v); }
__device__ inline void storev(float* p, float v) { *p = v; }

template<typename OUT>
__global__ __launch_bounds__(256) void ln_kernel(
    const float* __restrict__ x, const float* __restrict__ g, const float* __restrict__ b,
    OUT* __restrict__ out)
{
    __shared__ float red[8];
    long t = blockIdx.x;
    float e[3]; float s1 = 0.f, s2 = 0.f;
#pragma unroll
    for (int i = 0; i < 3; i++) {
        int c = threadIdx.x + i * 256;
        float v = x[t * D_ + c];
        e[i] = v; s1 += v; s2 += v * v;
    }
    for (int o = 32; o > 0; o >>= 1) { s1 += __shfl_down(s1, o); s2 += __shfl_down(s2, o); }
    if ((threadIdx.x & 63) == 0) { red[(threadIdx.x >> 6) * 2] = s1; red[(threadIdx.x >> 6) * 2 + 1] = s2; }
    __syncthreads();
    s1 = red[0] + red[2] + red[4] + red[6];
    s2 = red[1] + red[3] + red[5] + red[7];
    float mu = s1 * (1.f / D_);
    float var = s2 * (1.f / D_) - mu * mu;
    float rs = rsqrtf(var + EPS_);
#pragma unroll
    for (int i = 0; i < 3; i++) {
        int c = threadIdx.x + i * 256;
        storev(out + t * D_ + c, (e[i] - mu) * rs * g[c] + b[c]);
    }
}

// ---------------------------------------------------------------------------
// Row softmax over 512 cols (in-place, bf16), scale applied to logits.
// 256 threads, 2 cols/thread via 4B vector access.
// ---------------------------------------------------------------------------
__device__ inline float b2f(unsigned short h) {
    union { unsigned u; float f; } c; c.u = ((unsigned)h) << 16; return c.f;
}

__global__ __launch_bounds__(256) void softmax_kernel(bf16* __restrict__ s, float scale)
{
    __shared__ float red[4];
    long row = blockIdx.x;
    bf16* p = s + row * S_;
    ushort2 u = *(const ushort2*)(p + threadIdx.x * 2);
    float v0 = scale * b2f(u.x);
    float v1 = scale * b2f(u.y);
    float m = fmaxf(v0, v1);
    for (int o = 32; o > 0; o >>= 1) m = fmaxf(m, __shfl_down(m, o));
    if ((threadIdx.x & 63) == 0) red[threadIdx.x >> 6] = m;
    __syncthreads();
    m = fmaxf(fmaxf(red[0], red[1]), fmaxf(red[2], red[3]));
    __syncthreads();
    v0 = __expf(v0 - m); v1 = __expf(v1 - m);
    float sum = v0 + v1;
    for (int o = 32; o > 0; o >>= 1) sum += __shfl_down(sum, o);
    if ((threadIdx.x & 63) == 0) red[threadIdx.x >> 6] = sum;
    __syncthreads();
    sum = red[0] + red[1] + red[2] + red[3];
    float inv = 1.f / sum;
    bf16 o0 = __float2bfloat16(v0 * inv), o1 = __float2bfloat16(v1 * inv);
    ushort2 w; w.x = *(unsigned short*)&o0; w.y = *(unsigned short*)&o1;
    *(ushort2*)(p + threadIdx.x * 2) = w;
}

// ---------------------------------------------------------------------------
// MFMA GEMM (m97 structure): C[M,N] = A[M,K] * Bt[N,K]^T.
// 128x128 tile, BK=32, 4 waves x (4x4) 16x16x32 MFMAs.
// Staging: global_load_lds dwordx4, unpadded LDS 128x32, XOR k-chunk swizzle
//   (chunk ^= (row>>1)&3) so frag ds_read_b128 is 2-way banked (free).
// EPI 0: C -> bf16.
// EPI 1: relu(C + bias) -> bf16.
// EPI 2: Cf += C + bias (fp32); atomicAdd when ksplit>1 (bias on slice 0 only).
// EPI 3: QKV routing: col<768 -> Cb, <1536 -> Cb2, else Cb3 (ldc=768 each).
// z = (i1*batchH + i2)*ksplit + ks
// ---------------------------------------------------------------------------
template<int EPI>
__global__ __launch_bounds__(256) void gemm_bt(
    const bf16* __restrict__ A, const bf16* __restrict__ Bt,
    bf16* __restrict__ Cb, bf16* __restrict__ Cb2, bf16* __restrict__ Cb3,
    float* __restrict__ Cf, const float* __restrict__ bias,
    int M, int N, int K, int lda, int ldb, int ldc,
    int batchH, int ksplit,
    long sA1, long sA2, long sB1, long sB2, long sC1, long sC2)
{
    __shared__ __align__(16) bf16 As[128 * 32];
    __shared__ __align__(16) bf16 Bs[128 * 32];

    int zz = blockIdx.z;
    const int ks = zz % ksplit; zz /= ksplit;
    const int i1 = zz / batchH, i2 = zz - i1 * batchH;
    A  += i1 * sA1 + i2 * sA2;
    Bt += i1 * sB1 + i2 * sB2;
    const long coff = i1 * sC1 + i2 * sC2;

    const int Ks   = K / ksplit;
    const int kbeg = ks * Ks, kend = kbeg + Ks;

    const int tid  = threadIdx.x;
    const int lane = tid & 63, wave = tid >> 6;
    const int wm = wave >> 1, wn = wave & 1;
    const int lh = lane & 15, quad = lane >> 4;
    const int tileM = blockIdx.y * 128, tileN = blockIdx.x * 128;

    // staging lane decomposition: 4 lanes/row, 16 rows per wave-issue
    const int rl  = lane >> 2;                         // row within 16-row block
    const int gch = (lane & 3) ^ ((lane >> 3) & 3);    // swizzled global k-chunk
    // fragment read swizzle
    const int swz = (lh >> 1) & 3;

    floatx4 acc[4][4];
#pragma unroll
    for (int i = 0; i < 4; i++)
#pragma unroll
        for (int j = 0; j < 4; j++)
#pragma unroll
            for (int r = 0; r < 4; r++) acc[i][j][r] = 0.f;

    for (int kt = kbeg; kt < kend; kt += 32) {
#pragma unroll
        for (int it = 0; it < 2; it++) {
            const int q = wave * 2 + it;               // 16-row block index 0..7
            int ar = tileM + q * 16 + rl; if (ar >= M) ar = M - 1;
            GLOAD_LDS16(A + (long)ar * lda + kt + gch * 8, As + q * 512 + lane * 8);
            int br = tileN + q * 16 + rl; if (br >= N) br = N - 1;
            GLOAD_LDS16(Bt + (long)br * ldb + kt + gch * 8, Bs + q * 512 + lane * 8);
        }
        __syncthreads();   // drains vmcnt (compiler emits waitcnt before barrier)

        short8 af[4], bfr[4];
#pragma unroll
        for (int i = 0; i < 4; i++)
            af[i] = *(const short8*)(As + (wm * 64 + i * 16 + lh) * 32 + (quad ^ swz) * 8);
#pragma unroll
        for (int j = 0; j < 4; j++)
            bfr[j] = *(const short8*)(Bs + (wn * 64 + j * 16 + lh) * 32 + (quad ^ swz) * 8);
#pragma unroll
        for (int i = 0; i < 4; i++)
#pragma unroll
            for (int j = 0; j < 4; j++)
                acc[i][j] = __builtin_amdgcn_mfma_f32_16x16x32_bf16(af[i], bfr[j], acc[i][j], 0, 0, 0);
        __syncthreads();
    }

#pragma unroll
    for (int i = 0; i < 4; i++) {
#pragma unroll
        for (int j = 0; j < 4; j++) {
            int col = tileN + wn * 64 + j * 16 + lh;
            if (col >= N) continue;
#pragma unroll
            for (int r = 0; r < 4; r++) {
                int row = tileM + wm * 64 + i * 16 + quad * 4 + r;
                if (row >= M) continue;
                float v = acc[i][j][r];
                long o = coff + (long)row * ldc + col;
                if (EPI == 0) {
                    Cb[o] = __float2bfloat16(v);
                } else if (EPI == 1) {
                    v += bias[col];
                    Cb[o] = __float2bfloat16(v > 0.f ? v : 0.f);
                } else if (EPI == 2) {
                    if (ksplit > 1) {
                        atomicAdd(&Cf[o], v + (ks == 0 ? bias[col] : 0.f));
                    } else {
                        Cf[o] += v + bias[col];
                    }
                } else {
                    bf16* dst; int c2 = col;
                    if (c2 < 768)       { dst = Cb; }
                    else if (c2 < 1536) { dst = Cb2; c2 -= 768; }
                    else                { dst = Cb3; c2 -= 1536; }
                    dst[(long)row * 768 + c2] = __float2bfloat16(v);
                }
            }
        }
    }
}

// ---------------------------------------------------------------------------
extern "C" void kernel_launch(void* const* d_in, const int* in_sizes, int n_in,
                              void* d_out, int out_size, void* d_ws, size_t ws_size,
                              hipStream_t stream)
{
    const int*   idx  = (const int*)d_in[0];
    const float* tok  = (const float*)d_in[1];
    const float* segE = (const float*)d_in[2];
    const float* pos  = (const float*)d_in[3];
    const float* lng  = (const float*)d_in[4];
    const float* lnb  = (const float*)d_in[5];
    const float* Wq   = (const float*)d_in[6];
    const float* Wk   = (const float*)d_in[7];
    const float* Wv   = (const float*)d_in[8];
    const float* Wo   = (const float*)d_in[9];
    const float* bo   = (const float*)d_in[10];
    const float* ln1g = (const float*)d_in[11];
    const float* ln1b = (const float*)d_in[12];
    const float* ln2g = (const float*)d_in[13];
    const float* ln2b = (const float*)d_in[14];
    const float* W1   = (const float*)d_in[15];
    const float* b1   = (const float*)d_in[16];
    const float* W2   = (const float*)d_in[17];
    const float* b2   = (const float*)d_in[18];
    const float* lnfg = (const float*)d_in[19];
    const float* lnfb = (const float*)d_in[20];

    char* w = (char*)d_ws;
    size_t off = 0;
    auto alloc = [&](size_t bytes) { void* p = w + off; off += (bytes + 255) & ~255UL; return p; };

    const long DD  = (long)D_ * D_;          // 589824
    const long DF  = (long)D_ * FF_;         // 2359296
    bf16* WqkvT = (bf16*)alloc((size_t)L_ * 3 * DD * 2);   // (L, 3, 768, 768) rows=outcol(h-major), cols=d
    bf16* WoT   = (bf16*)alloc((size_t)L_ * DD * 2);
    bf16* W1T   = (bf16*)alloc((size_t)L_ * DF * 2);
    bf16* W2T   = (bf16*)alloc((size_t)L_ * DF * 2);
    float* x  = (float*)alloc((size_t)B_ * S_ * D_ * 4);
    bf16* h   = (bf16*)alloc((size_t)B_ * S_ * D_ * 2);
    bf16* qb  = (bf16*)alloc((size_t)B_ * S_ * D_ * 2);   // also reused as o (attn out)
    bf16* kb  = (bf16*)alloc((size_t)B_ * S_ * D_ * 2);
    bf16* vb  = (bf16*)alloc((size_t)B_ * S_ * D_ * 2);
    bf16* vt  = (bf16*)alloc((size_t)B_ * S_ * D_ * 2);
    bf16* sb  = (bf16*)alloc((size_t)B_ * H_ * S_ * S_ * 2);  // scores/probs
    bf16* ff  = sb;   // FF1 output (50 MB) aliases scores (100 MB) — disjoint in time
    (void)ws_size; (void)n_in; (void)in_sizes; (void)out_size;

    dim3 blk256(256), blkT(32, 8);

    // ---- weight prep (bf16, (N,K) row-major) ----
    // Wq (L,H,768,64) -> WqkvT rows [0,768)  per layer; z=(l,h)
    wtrans_kernel<<<dim3(2, 24, L_ * H_), blkT, 0, stream>>>(Wq, WqkvT,            D_, DH_, H_, 3 * DD, (long)DH_ * D_);
    wtrans_kernel<<<dim3(2, 24, L_ * H_), blkT, 0, stream>>>(Wk, WqkvT + DD,       D_, DH_, H_, 3 * DD, (long)DH_ * D_);
    wtrans_kernel<<<dim3(2, 24, L_ * H_), blkT, 0, stream>>>(Wv, WqkvT + 2 * DD,   D_, DH_, H_, 3 * DD, (long)DH_ * D_);
    wtrans_kernel<<<dim3(24, 24, L_), blkT, 0, stream>>>(Wo, WoT, D_, D_, 1, DD, 0);
    wtrans_kernel<<<dim3(96, 24, L_), blkT, 0, stream>>>(W1, W1T, D_, FF_, 1, DF, 0);
    wtrans_kernel<<<dim3(24, 96, L_), blkT, 0, stream>>>(W2, W2T, FF_, D_, 1, DF, 0);

    // ---- embedding + LN ----
    embed_ln_kernel<<<dim3(B_ * S_), blk256, 0, stream>>>(idx, tok, segE, pos, lng, lnb, x);

    const int M = B_ * S_;                  // 8192
    const long sBH = (long)S_ * D_;         // per-b stride in q/k/v
    const long sSS = (long)S_ * S_;

    for (int l = 0; l < L_; l++) {
        // h = LN1(x)
        ln_kernel<bf16><<<dim3(M), blk256, 0, stream>>>(x, ln1g + l * D_, ln1b + l * D_, h);
        // fused QKV projection: N = 2304
        gemm_bt<3><<<dim3(18, 64, 1), blk256, 0, stream>>>(h, WqkvT + l * 3 * DD, qb, kb, vb, nullptr, nullptr,
            M, 3 * D_, D_, D_, D_, D_, 1, 1, 0, 0, 0, 0, 0, 0);
        // vt (b,h,dh,s)
        transpose_v_kernel<<<dim3(S_ / 32, DH_ / 32, B_ * H_), blkT, 0, stream>>>(vb, vt);
        // scores = Q K^T  (batched over b*h)
        gemm_bt<0><<<dim3(4, 4, B_ * H_), blk256, 0, stream>>>(qb, kb, sb, nullptr, nullptr, nullptr, nullptr,
            S_, S_, DH_, D_, D_, S_, H_, 1,
            sBH, DH_, sBH, DH_, (long)H_ * sSS, sSS);
        // softmax rows (scale 1/sqrt(64))
        softmax_kernel<<<dim3(B_ * H_ * S_), blk256, 0, stream>>>(sb, 0.125f);
        // o = P V   (batched; C written into qb at (b,s,h,dh))
        gemm_bt<0><<<dim3(1, 4, B_ * H_), blk256, 0, stream>>>(sb, vt, qb, nullptr, nullptr, nullptr, nullptr,
            S_, DH_, S_, S_, S_, D_, H_, 1,
            (long)H_ * sSS, sSS, (long)H_ * DH_ * S_, (long)DH_ * S_, sBH, (long)DH_);
        // x += o @ Wo + bo
        gemm_bt<2><<<dim3(6, 64, 1), blk256, 0, stream>>>(qb, WoT + l * DD, nullptr, nullptr, nullptr, x, bo + l * D_,
            M, D_, D_, D_, D_, D_, 1, 1, 0, 0, 0, 0, 0, 0);
        // h = LN2(x)
        ln_kernel<bf16><<<dim3(M), blk256, 0, stream>>>(x, ln2g + l * D_, ln2b + l * D_, h);
        // ff = relu(h @ W1 + b1)
        gemm_bt<1><<<dim3(24, 64, 1), blk256, 0, stream>>>(h, W1T + l * DF, ff, nullptr, nullptr, nullptr, b1 + l * FF_,
            M, FF_, D_, D_, D_, FF_, 1, 1, 0, 0, 0, 0, 0, 0);
        // x += ff @ W2 + b2   (split-K=2 for occupancy: grid 384 -> 768 blocks)
        gemm_bt<2><<<dim3(6, 64, 2), blk256, 0, stream>>>(ff, W2T + l * DF, nullptr, nullptr, nullptr, x, b2 + l * D_,
            M, D_, FF_, FF_, FF_, D_, 1, 2, 0, 0, 0, 0, 0, 0);
    }

    // final LN -> d_out (fp32)
    ln_kernel<float><<<dim3(M), blk256, 0, stream>>>(x, lnfg, lnfb, (float*)d_out);
}

// Round 3
// 4051.167 us; speedup vs baseline: 1.8540x; 1.4010x over previous
//
#include <hip/hip_runtime.h>
#include <hip/hip_bf16.h>

#define B_  16
#define S_  512
#define D_  768
#define H_  12
#define DH_ 64
#define L_  12
#define FF_ 3072
#define EPS_ 1e-5f

typedef __hip_bfloat16 bf16;
typedef __attribute__((ext_vector_type(8))) short short8;   // 8 bf16 = 4 VGPRs (MFMA A/B frag)
typedef __attribute__((ext_vector_type(4))) float floatx4;  // MFMA C/D frag

// direct global->LDS, 16B per lane; LDS dest = wave-uniform base + lane*16
#define GLOAD_LDS16(g, l) __builtin_amdgcn_global_load_lds( \
    (const __attribute__((address_space(1))) unsigned int*)(g), \
    (__attribute__((address_space(3))) unsigned int*)(l), 16, 0, 0)

__device__ inline unsigned short f2b(float v) {
    __hip_bfloat16 t = __float2bfloat16(v);
    return *(unsigned short*)&t;
}

// ---------------------------------------------------------------------------
// Weight transpose+convert: in (z, R, C) fp32 -> out (i1*os1 + i2*os2) (C, R) bf16
// ---------------------------------------------------------------------------
__global__ void wtrans_kernel(const float* __restrict__ in, bf16* __restrict__ out,
                              int R, int C, int batchH, long os1, long os2)
{
    __shared__ float tile[32][33];
    int z = blockIdx.z;
    int i1 = z / batchH, i2 = z - i1 * batchH;
    const float* ip = in + (long)z * R * C;
    bf16* op = out + i1 * os1 + i2 * os2;
    int r0 = blockIdx.y * 32, c0 = blockIdx.x * 32;
    for (int i = threadIdx.y; i < 32; i += 8)
        tile[i][threadIdx.x] = ip[(long)(r0 + i) * C + c0 + threadIdx.x];
    __syncthreads();
    for (int i = threadIdx.y; i < 32; i += 8)
        op[(long)(c0 + i) * R + r0 + threadIdx.x] = __float2bfloat16(tile[threadIdx.x][i]);
}

// ---------------------------------------------------------------------------
// V transpose: v (b, s, h, dh) bf16 -> vt (b, h, dh, s) bf16
// ---------------------------------------------------------------------------
__global__ void transpose_v_kernel(const bf16* __restrict__ v, bf16* __restrict__ vt)
{
    __shared__ bf16 tile[32][33];
    int bh = blockIdx.z;
    int b = bh / H_, h = bh - b * H_;
    int s0 = blockIdx.x * 32, d0 = blockIdx.y * 32;
    for (int i = threadIdx.y; i < 32; i += 8)
        tile[i][threadIdx.x] = v[((long)(b * S_ + s0 + i)) * D_ + h * DH_ + d0 + threadIdx.x];
    __syncthreads();
    for (int i = threadIdx.y; i < 32; i += 8)
        vt[((long)bh * DH_ + d0 + i) * S_ + s0 + threadIdx.x] = tile[threadIdx.x][i];
}

// ---------------------------------------------------------------------------
// Embedding + LayerNorm -> x fp32.
// ---------------------------------------------------------------------------
__global__ __launch_bounds__(256) void embed_ln_kernel(
    const int* __restrict__ idx, const float* __restrict__ tok,
    const float* __restrict__ seg, const float* __restrict__ pos,
    const float* __restrict__ g, const float* __restrict__ b,
    float* __restrict__ x)
{
    __shared__ float red[8];
    int t = blockIdx.x;
    int si = t & (S_ - 1);
    int token = idx[t];
    int sg = (si >= S_ / 2 + 1) ? 1 : 0;
    float e[3]; float s1 = 0.f, s2 = 0.f;
#pragma unroll
    for (int i = 0; i < 3; i++) {
        int c = threadIdx.x + i * 256;
        float v = tok[(long)token * D_ + c] + seg[sg * D_ + c] + pos[(long)si * D_ + c];
        e[i] = v; s1 += v; s2 += v * v;
    }
    for (int o = 32; o > 0; o >>= 1) { s1 += __shfl_down(s1, o); s2 += __shfl_down(s2, o); }
    if ((threadIdx.x & 63) == 0) { red[(threadIdx.x >> 6) * 2] = s1; red[(threadIdx.x >> 6) * 2 + 1] = s2; }
    __syncthreads();
    s1 = red[0] + red[2] + red[4] + red[6];
    s2 = red[1] + red[3] + red[5] + red[7];
    float mu = s1 * (1.f / D_);
    float var = s2 * (1.f / D_) - mu * mu;
    float rs = rsqrtf(var + EPS_);
#pragma unroll
    for (int i = 0; i < 3; i++) {
        int c = threadIdx.x + i * 256;
        x[(long)t * D_ + c] = (e[i] - mu) * rs * g[c] + b[c];
    }
}

// ---------------------------------------------------------------------------
// LayerNorm: x fp32 -> out (bf16 or fp32).
// ---------------------------------------------------------------------------
__device__ inline void storev(bf16* p, float v)  { *p = __float2bfloat16(v); }
__device__ inline void storev(float* p, float v) { *p = v; }

template<typename OUT>
__global__ __launch_bounds__(256) void ln_kernel(
    const float* __restrict__ x, const float* __restrict__ g, const float* __restrict__ b,
    OUT* __restrict__ out)
{
    __shared__ float red[8];
    long t = blockIdx.x;
    float e[3]; float s1 = 0.f, s2 = 0.f;
#pragma unroll
    for (int i = 0; i < 3; i++) {
        int c = threadIdx.x + i * 256;
        float v = x[t * D_ + c];
        e[i] = v; s1 += v; s2 += v * v;
    }
    for (int o = 32; o > 0; o >>= 1) { s1 += __shfl_down(s1, o); s2 += __shfl_down(s2, o); }
    if ((threadIdx.x & 63) == 0) { red[(threadIdx.x >> 6) * 2] = s1; red[(threadIdx.x >> 6) * 2 + 1] = s2; }
    __syncthreads();
    s1 = red[0] + red[2] + red[4] + red[6];
    s2 = red[1] + red[3] + red[5] + red[7];
    float mu = s1 * (1.f / D_);
    float var = s2 * (1.f / D_) - mu * mu;
    float rs = rsqrtf(var + EPS_);
#pragma unroll
    for (int i = 0; i < 3; i++) {
        int c = threadIdx.x + i * 256;
        storev(out + t * D_ + c, (e[i] - mu) * rs * g[c] + b[c]);
    }
}

// ---------------------------------------------------------------------------
// Fused flash attention (S^T orientation).
// Grid: (S/128, B*H).  Block: 256 thr = 4 waves; wave w owns q-cols [w*32,w*32+32).
// Per kv-tile (128): stage K(128x64),V^T(64x128) -> S^T = K·Q^T (MFMA) ->
// online softmax over q-columns (2 shfl_xor reductions) -> P^T via LDS (b64
// writes, b128 reads) -> O^T += V^T·P^T.  Epilogue: LDS transpose -> coalesced.
// All LDS tiles XOR-swizzled so frag ds_reads are ~2-way banked.
// ---------------------------------------------------------------------------
__global__ __launch_bounds__(256) void flash_attn_kernel(
    const bf16* __restrict__ qg, const bf16* __restrict__ kg,
    const bf16* __restrict__ vtg, bf16* __restrict__ og)
{
    __shared__ __align__(16) bf16 Qs[128 * 64];       // [qrow][dh]  row%8 XOR-swizzled chunks
    __shared__ __align__(16) bf16 Ks[128 * 64];       // [kvrow][dh] same
    __shared__ __align__(16) bf16 Vs[64 * 128];       // [dh][kv]    row%16 XOR-swizzled
    __shared__ __align__(16) bf16 Ps[4 * 32 * 64];    // per-wave P^T half-tile / Os scratch

    const int bh = blockIdx.y;
    const int b  = bh / H_, hh = bh - b * H_;
    const int q0 = blockIdx.x * 128;

    const int tid  = threadIdx.x;
    const int lane = tid & 63, wave = tid >> 6;
    const int lh = lane & 15, quad = lane >> 4;
    const int lh7 = lh & 7;

    const bf16* qbase = qg + ((long)(b * S_ + q0)) * D_ + hh * DH_;
    const bf16* kbase = kg + ((long)(b * S_)) * D_ + hh * DH_;
    const bf16* vbase = vtg + ((long)bh * DH_) * S_;

    const int rl8 = lane >> 3, cl8 = lane & 7;        // 8 rows x 8 chunks (Q/K)
    const int gch8 = cl8 ^ rl8;
    const int rv = lane >> 4, cl16 = lane & 15;       // 4 rows x 16 chunks (V^T)

    // ---- load Q tile (once) ----
#pragma unroll
    for (int it = 0; it < 4; it++) {
        int q = wave * 4 + it;
        GLOAD_LDS16(qbase + (long)(q * 8 + rl8) * D_ + gch8 * 8, Qs + q * 512 + lane * 8);
    }

    floatx4 ofr[4][2];
#pragma unroll
    for (int i = 0; i < 4; i++)
#pragma unroll
        for (int j = 0; j < 2; j++)
#pragma unroll
            for (int r = 0; r < 4; r++) ofr[i][j][r] = 0.f;
    float m_[2] = { -1e30f, -1e30f }, l_[2] = { 0.f, 0.f };

    for (int kv = 0; kv < S_; kv += 128) {
        // ---- stage K tile + V^T tile ----
#pragma unroll
        for (int it = 0; it < 4; it++) {
            int q = wave * 4 + it;
            GLOAD_LDS16(kbase + (long)(kv + q * 8 + rl8) * D_ + gch8 * 8, Ks + q * 512 + lane * 8);
            int d = q * 4 + rv;
            int gcv = cl16 ^ (d & 15);
            GLOAD_LDS16(vbase + (long)d * S_ + kv + gcv * 8, Vs + q * 512 + lane * 8);
        }
        __syncthreads();

        // ---- S^T = K · Q^T ----
        floatx4 sfr[8][2];
#pragma unroll
        for (int i = 0; i < 8; i++)
#pragma unroll
            for (int j = 0; j < 2; j++)
#pragma unroll
                for (int r = 0; r < 4; r++) sfr[i][j][r] = 0.f;

        short8 bq[2][2];
#pragma unroll
        for (int ks = 0; ks < 2; ks++)
#pragma unroll
            for (int nf = 0; nf < 2; nf++)
                bq[ks][nf] = *(const short8*)(Qs + (wave * 32 + nf * 16 + lh) * 64 +
                                              (((ks * 4 + quad) ^ lh7) * 8));
#pragma unroll
        for (int mf = 0; mf < 8; mf++) {
#pragma unroll
            for (int ks = 0; ks < 2; ks++) {
                short8 ak = *(const short8*)(Ks + (mf * 16 + lh) * 64 +
                                             (((ks * 4 + quad) ^ lh7) * 8));
#pragma unroll
                for (int nf = 0; nf < 2; nf++)
                    sfr[mf][nf] = __builtin_amdgcn_mfma_f32_16x16x32_bf16(ak, bq[ks][nf], sfr[mf][nf], 0, 0, 0);
            }
        }

        // ---- online softmax per q-column (i = wave*32 + nf*16 + lh) ----
#pragma unroll
        for (int nf = 0; nf < 2; nf++) {
            float mx = -1e30f;
#pragma unroll
            for (int mf = 0; mf < 8; mf++)
#pragma unroll
                for (int r = 0; r < 4; r++) mx = fmaxf(mx, sfr[mf][nf][r]);
            mx = fmaxf(mx, __shfl_xor(mx, 16));
            mx = fmaxf(mx, __shfl_xor(mx, 32));
            float mnew = fmaxf(m_[nf], mx * 0.125f);
            float alpha = __expf(m_[nf] - mnew);
            m_[nf] = mnew;
            float rs = 0.f;
#pragma unroll
            for (int mf = 0; mf < 8; mf++)
#pragma unroll
                for (int r = 0; r < 4; r++) {
                    float p = __expf(sfr[mf][nf][r] * 0.125f - mnew);
                    sfr[mf][nf][r] = p; rs += p;
                }
            rs += __shfl_xor(rs, 16);
            rs += __shfl_xor(rs, 32);
            l_[nf] = l_[nf] * alpha + rs;
#pragma unroll
            for (int mo = 0; mo < 4; mo++)
#pragma unroll
                for (int r = 0; r < 4; r++) ofr[mo][nf][r] *= alpha;
        }

        // ---- PV in two k-halves (P^T via per-wave LDS roundtrip) ----
#pragma unroll
        for (int half = 0; half < 2; half++) {
#pragma unroll
            for (int mf2 = 0; mf2 < 4; mf2++) {
                int mf = half * 4 + mf2;
#pragma unroll
                for (int nf = 0; nf < 2; nf++) {
                    ushort4 pk;
                    pk.x = f2b(sfr[mf][nf][0]); pk.y = f2b(sfr[mf][nf][1]);
                    pk.z = f2b(sfr[mf][nf][2]); pk.w = f2b(sfr[mf][nf][3]);
                    int iloc = nf * 16 + lh;
                    int c8 = (mf2 * 2 + (quad >> 1)) ^ lh7;
                    *(ushort4*)(Ps + wave * 2048 + iloc * 64 + c8 * 8 + (quad & 1) * 4) = pk;
                }
            }
#pragma unroll
            for (int ksl = 0; ksl < 2; ksl++) {
                int ksg = half * 2 + ksl;
                short8 bp[2];
#pragma unroll
                for (int nf = 0; nf < 2; nf++)
                    bp[nf] = *(const short8*)(Ps + wave * 2048 + (nf * 16 + lh) * 64 +
                                              (((ksl * 4 + quad) ^ lh7) * 8));
#pragma unroll
                for (int mo = 0; mo < 4; mo++) {
                    short8 av = *(const short8*)(Vs + (mo * 16 + lh) * 128 +
                                                 (((ksg * 4 + quad) ^ lh) * 8));
#pragma unroll
                    for (int nf = 0; nf < 2; nf++)
                        ofr[mo][nf] = __builtin_amdgcn_mfma_f32_16x16x32_bf16(av, bp[nf], ofr[mo][nf], 0, 0, 0);
                }
            }
        }
        __syncthreads();
    }

    // ---- normalize + transpose through LDS -> coalesced global store ----
    float inv[2] = { 1.f / l_[0], 1.f / l_[1] };
#pragma unroll
    for (int mo = 0; mo < 4; mo++)
#pragma unroll
        for (int nf = 0; nf < 2; nf++) {
            ushort4 pk;
            pk.x = f2b(ofr[mo][nf][0] * inv[nf]); pk.y = f2b(ofr[mo][nf][1] * inv[nf]);
            pk.z = f2b(ofr[mo][nf][2] * inv[nf]); pk.w = f2b(ofr[mo][nf][3] * inv[nf]);
            int iloc = nf * 16 + lh;
            int c8 = (mo * 2 + (quad >> 1)) ^ (iloc & 7);
            *(ushort4*)(Ps + wave * 2048 + iloc * 64 + c8 * 8 + (quad & 1) * 4) = pk;
        }
#pragma unroll
    for (int t = 0; t < 4; t++) {
        int iloc = t * 8 + rl8;
        short8 vv = *(const short8*)(Ps + wave * 2048 + iloc * 64 + ((cl8 ^ (iloc & 7)) * 8));
        long row = (long)(b * S_ + q0 + wave * 32 + iloc);
        *(uint4*)(og + row * D_ + hh * DH_ + cl8 * 8) = *(uint4*)&vv;
    }
}

// ---------------------------------------------------------------------------
// MFMA GEMM: C[M,N] = A[M,K] * Bt[N,K]^T.  128x128 tile, BK=64, 4 waves.
// global_load_lds dwordx4 staging, XOR-8 k-chunk swizzle (conflict-free).
// All dims assumed exact multiples of the tile (true for every call site).
// EPI 1: relu(C + bias) -> bf16.
// EPI 2: Cf += C + bias (fp32); atomicAdd when ksplit>1 (bias on slice 0).
// EPI 3: QKV routing: col<768 -> Cb, <1536 -> Cb2, else Cb3 (ldc=768 each).
// ---------------------------------------------------------------------------
template<int EPI>
__global__ __launch_bounds__(256) void gemm_bt(
    const bf16* __restrict__ A, const bf16* __restrict__ Bt,
    bf16* __restrict__ Cb, bf16* __restrict__ Cb2, bf16* __restrict__ Cb3,
    float* __restrict__ Cf, const float* __restrict__ bias,
    int M, int N, int K, int lda, int ldb, int ldc, int ksplit)
{
    __shared__ __align__(16) bf16 As[128 * 64];
    __shared__ __align__(16) bf16 Bs[128 * 64];

    const int ks_id = blockIdx.z;
    const int Ks   = K / ksplit;
    const int kbeg = ks_id * Ks, kend = kbeg + Ks;

    const int tid  = threadIdx.x;
    const int lane = tid & 63, wave = tid >> 6;
    const int wm = wave >> 1, wn = wave & 1;
    const int lh = lane & 15, quad = lane >> 4;
    const int lh7 = lh & 7;
    const int tileM = blockIdx.y * 128, tileN = blockIdx.x * 128;

    const int rl8 = lane >> 3, cl8 = lane & 7;
    const int gch = cl8 ^ rl8;

    floatx4 acc[4][4];
#pragma unroll
    for (int i = 0; i < 4; i++)
#pragma unroll
        for (int j = 0; j < 4; j++)
#pragma unroll
            for (int r = 0; r < 4; r++) acc[i][j][r] = 0.f;

    for (int kt = kbeg; kt < kend; kt += 64) {
#pragma unroll
        for (int it = 0; it < 4; it++) {
            const int q = wave * 4 + it;               // 8-row block 0..15
            GLOAD_LDS16(A + (long)(tileM + q * 8 + rl8) * lda + kt + gch * 8, As + q * 512 + lane * 8);
            GLOAD_LDS16(Bt + (long)(tileN + q * 8 + rl8) * ldb + kt + gch * 8, Bs + q * 512 + lane * 8);
        }
        __syncthreads();

#pragma unroll
        for (int ks = 0; ks < 2; ks++) {
            short8 af[4], bfr[4];
#pragma unroll
            for (int i = 0; i < 4; i++)
                af[i] = *(const short8*)(As + (wm * 64 + i * 16 + lh) * 64 + (((ks * 4 + quad) ^ lh7) * 8));
#pragma unroll
            for (int j = 0; j < 4; j++)
                bfr[j] = *(const short8*)(Bs + (wn * 64 + j * 16 + lh) * 64 + (((ks * 4 + quad) ^ lh7) * 8));
#pragma unroll
            for (int i = 0; i < 4; i++)
#pragma unroll
                for (int j = 0; j < 4; j++)
                    acc[i][j] = __builtin_amdgcn_mfma_f32_16x16x32_bf16(af[i], bfr[j], acc[i][j], 0, 0, 0);
        }
        __syncthreads();
    }

#pragma unroll
    for (int i = 0; i < 4; i++) {
#pragma unroll
        for (int j = 0; j < 4; j++) {
            int col = tileN + wn * 64 + j * 16 + lh;
#pragma unroll
            for (int r = 0; r < 4; r++) {
                int row = tileM + wm * 64 + i * 16 + quad * 4 + r;
                float v = acc[i][j][r];
                long o = (long)row * ldc + col;
                if (EPI == 1) {
                    v += bias[col];
                    Cb[o] = __float2bfloat16(v > 0.f ? v : 0.f);
                } else if (EPI == 2) {
                    if (ksplit > 1) {
                        atomicAdd(&Cf[o], v + (ks_id == 0 ? bias[col] : 0.f));
                    } else {
                        Cf[o] += v + bias[col];
                    }
                } else {
                    bf16* dst; int c2 = col;
                    if (c2 < 768)       { dst = Cb; }
                    else if (c2 < 1536) { dst = Cb2; c2 -= 768; }
                    else                { dst = Cb3; c2 -= 1536; }
                    dst[(long)row * 768 + c2] = __float2bfloat16(v);
                }
            }
        }
    }
}

// ---------------------------------------------------------------------------
extern "C" void kernel_launch(void* const* d_in, const int* in_sizes, int n_in,
                              void* d_out, int out_size, void* d_ws, size_t ws_size,
                              hipStream_t stream)
{
    const int*   idx  = (const int*)d_in[0];
    const float* tok  = (const float*)d_in[1];
    const float* segE = (const float*)d_in[2];
    const float* pos  = (const float*)d_in[3];
    const float* lng  = (const float*)d_in[4];
    const float* lnb  = (const float*)d_in[5];
    const float* Wq   = (const float*)d_in[6];
    const float* Wk   = (const float*)d_in[7];
    const float* Wv   = (const float*)d_in[8];
    const float* Wo   = (const float*)d_in[9];
    const float* bo   = (const float*)d_in[10];
    const float* ln1g = (const float*)d_in[11];
    const float* ln1b = (const float*)d_in[12];
    const float* ln2g = (const float*)d_in[13];
    const float* ln2b = (const float*)d_in[14];
    const float* W1   = (const float*)d_in[15];
    const float* b1   = (const float*)d_in[16];
    const float* W2   = (const float*)d_in[17];
    const float* b2   = (const float*)d_in[18];
    const float* lnfg = (const float*)d_in[19];
    const float* lnfb = (const float*)d_in[20];

    char* w = (char*)d_ws;
    size_t off = 0;
    auto alloc = [&](size_t bytes) { void* p = w + off; off += (bytes + 255) & ~255UL; return p; };

    const long DD  = (long)D_ * D_;
    const long DF  = (long)D_ * FF_;
    bf16* WqkvT = (bf16*)alloc((size_t)L_ * 3 * DD * 2);
    bf16* WoT   = (bf16*)alloc((size_t)L_ * DD * 2);
    bf16* W1T   = (bf16*)alloc((size_t)L_ * DF * 2);
    bf16* W2T   = (bf16*)alloc((size_t)L_ * DF * 2);
    float* x  = (float*)alloc((size_t)B_ * S_ * D_ * 4);
    bf16* h   = (bf16*)alloc((size_t)B_ * S_ * D_ * 2);
    bf16* qb  = (bf16*)alloc((size_t)B_ * S_ * D_ * 2);
    bf16* kb  = (bf16*)alloc((size_t)B_ * S_ * D_ * 2);
    bf16* vb  = (bf16*)alloc((size_t)B_ * S_ * D_ * 2);
    bf16* vt  = (bf16*)alloc((size_t)B_ * S_ * D_ * 2);
    bf16* ob  = (bf16*)alloc((size_t)B_ * S_ * D_ * 2);   // attention output
    bf16* ff  = (bf16*)alloc((size_t)B_ * S_ * FF_ * 2);
    (void)ws_size; (void)n_in; (void)in_sizes; (void)out_size;

    dim3 blk256(256), blkT(32, 8);

    // ---- weight prep (bf16, (N,K) row-major) ----
    wtrans_kernel<<<dim3(2, 24, L_ * H_), blkT, 0, stream>>>(Wq, WqkvT,          D_, DH_, H_, 3 * DD, (long)DH_ * D_);
    wtrans_kernel<<<dim3(2, 24, L_ * H_), blkT, 0, stream>>>(Wk, WqkvT + DD,     D_, DH_, H_, 3 * DD, (long)DH_ * D_);
    wtrans_kernel<<<dim3(2, 24, L_ * H_), blkT, 0, stream>>>(Wv, WqkvT + 2 * DD, D_, DH_, H_, 3 * DD, (long)DH_ * D_);
    wtrans_kernel<<<dim3(24, 24, L_), blkT, 0, stream>>>(Wo, WoT, D_, D_, 1, DD, 0);
    wtrans_kernel<<<dim3(96, 24, L_), blkT, 0, stream>>>(W1, W1T, D_, FF_, 1, DF, 0);
    wtrans_kernel<<<dim3(24, 96, L_), blkT, 0, stream>>>(W2, W2T, FF_, D_, 1, DF, 0);

    // ---- embedding + LN ----
    embed_ln_kernel<<<dim3(B_ * S_), blk256, 0, stream>>>(idx, tok, segE, pos, lng, lnb, x);

    const int M = B_ * S_;   // 8192

    for (int l = 0; l < L_; l++) {
        // h = LN1(x)
        ln_kernel<bf16><<<dim3(M), blk256, 0, stream>>>(x, ln1g + l * D_, ln1b + l * D_, h);
        // fused QKV projection: N = 2304, routed into qb/kb/vb
        gemm_bt<3><<<dim3(18, 64, 1), blk256, 0, stream>>>(h, WqkvT + l * 3 * DD, qb, kb, vb, nullptr, nullptr,
            M, 3 * D_, D_, D_, D_, 3 * D_, 1);
        // vt (b,h,dh,s)
        transpose_v_kernel<<<dim3(S_ / 32, DH_ / 32, B_ * H_), blkT, 0, stream>>>(vb, vt);
        // fused attention -> ob (b,s,h,dh)
        flash_attn_kernel<<<dim3(S_ / 128, B_ * H_), blk256, 0, stream>>>(qb, kb, vt, ob);
        // x += ob @ Wo + bo   (split-K=2)
        gemm_bt<2><<<dim3(6, 64, 2), blk256, 0, stream>>>(ob, WoT + l * DD, nullptr, nullptr, nullptr, x, bo + l * D_,
            M, D_, D_, D_, D_, D_, 2);
        // h = LN2(x)
        ln_kernel<bf16><<<dim3(M), blk256, 0, stream>>>(x, ln2g + l * D_, ln2b + l * D_, h);
        // ff = relu(h @ W1 + b1)
        gemm_bt<1><<<dim3(24, 64, 1), blk256, 0, stream>>>(h, W1T + l * DF, ff, nullptr, nullptr, nullptr, b1 + l * FF_,
            M, FF_, D_, D_, D_, FF_, 1);
        // x += ff @ W2 + b2   (split-K=2)
        gemm_bt<2><<<dim3(6, 64, 2), blk256, 0, stream>>>(ff, W2T + l * DF, nullptr, nullptr, nullptr, x, b2 + l * D_,
            M, D_, FF_, FF_, FF_, D_, 2);
    }

    // final LN -> d_out (fp32)
    ln_kernel<float><<<dim3(M), blk256, 0, stream>>>(x, lnfg, lnfb, (float*)d_out);
}